// Round 8
// baseline (410.597 us; speedup 1.0000x reference)
//
#include <hip/hip_runtime.h>

// Problem constants (fixed by setup_inputs + SCALE_FACTOR=2 branch):
//   B=8, N=1024, C=128, N0=16384, output grid H=W=256
constexpr int B  = 8;
constexpr int N  = 1024;
constexpr int C  = 128;
constexpr int N0 = 16384;
constexpr int HH = 256;
constexpr int WW = 256;
constexpr int HW = HH * WW;                 // 65536 cells/batch
constexpr int NPTS = B * N0;                // 131072 points

constexpr int STRIP  = 2048;                // cells per output block -> 8 KB contiguous store
constexpr int SPB    = HW / STRIP;          // 32 strips/batch
constexpr int NSTRIP = B * SPB;             // 256 strips
constexpr int CAP    = 768;                 // recs per strip (mean 512, +11 sigma)

// Bit-exact replica of the reference cell computation (validated R1-R7):
__device__ __forceinline__ int cell_of(float lx, float ly) {
    lx = fminf(fmaxf(lx, -1.0f), 1.0f);
    ly = fminf(fmaxf(ly, -1.0f), 1.0f);
    float pxf = rintf(0.5f * (lx + 1.0f) * 256.0f - 0.5f);  // RNE == jnp.round
    float pyf = rintf(0.5f * (ly + 1.0f) * 256.0f - 0.5f);
    int ix = (int)pxf; ix = ix < 0 ? 0 : (ix > WW - 1 ? WW - 1 : ix);
    int iy = (int)pyf; iy = iy < 0 ? 0 : (iy > HH - 1 ? HH - 1 : iy);
    return iy * WW + ix;
}

// ---- Pass A: transpose x [B][N][C] -> xT [B][C][N] (4 MB, validated R6) --
__global__ __launch_bounds__(256) void transpose_kernel(const float* __restrict__ x,
                                                        float* __restrict__ xT) {
    __shared__ float tile[64][C + 1];
    int blk  = blockIdx.x;                      // 128 blocks
    int b    = blk >> 4;
    int tok0 = (blk & 15) * 64;
    int tid  = threadIdx.x;
    for (int it = 0; it < 8; ++it) {
        int f  = it * 256 + tid;
        int tl = f >> 5;
        int c4 = (f & 31) * 4;
        float4 v = *(const float4*)(x + ((size_t)(b * N + tok0 + tl) * C + c4));
        tile[tl][c4 + 0] = v.x; tile[tl][c4 + 1] = v.y;
        tile[tl][c4 + 2] = v.z; tile[tl][c4 + 3] = v.w;
    }
    __syncthreads();
    for (int it = 0; it < 32; ++it) {
        int f  = it * 256 + tid;
        int c  = f >> 6;
        int tl = f & 63;
        xT[(size_t)(b * C + c) * N + tok0 + tl] = tile[tl][c];
    }
}

// ---- Pass B: counting-sort points by strip + global per-cell counts ------
// rec = (local_cell << 10) | tok   (local < 2048 -> 11 bits, tok < 1024)
__global__ void bucket_kernel(const float* __restrict__ loc_orig,
                              const int* __restrict__ idx_agg,
                              int* __restrict__ cursor,
                              int* __restrict__ bucket,
                              float* __restrict__ cnts) {
    int p = blockIdx.x * blockDim.x + threadIdx.x;
    if (p >= NPTS) return;
    float2 l = ((const float2*)loc_orig)[p];
    int b = p >> 14;                            // N0 = 2^14
    int cell = cell_of(l.x, l.y);
    int s = b * SPB + (cell >> 11);             // STRIP = 2048
    int pos = atomicAdd(cursor + s, 1);
    if (pos < CAP) bucket[s * CAP + pos] = ((cell & 2047) << 10) | idx_agg[p];
    atomicAdd(cnts + b * HW + cell, 1.0f);
}

// ---- Pass C: one block per (b,c,strip); 8 KB contiguous store ------------
// Consecutive blocks write consecutive 8 KB spans (fill-kernel-like stream).
__global__ __launch_bounds__(256) void strip_kernel(
        const float* __restrict__ xT,
        const int* __restrict__ cursor,
        const int* __restrict__ bucket,
        const float* __restrict__ cnts,
        float* __restrict__ out) {
    __shared__ float acc[STRIP];                // 8 KB
    __shared__ float xc[N];                     // 4 KB
    __shared__ int   recs[CAP];                 // 3 KB
    __shared__ int   cnt_s;

    int gid = blockIdx.x;                       // ((b*C + c) * SPB + s), s fastest
    int s   = gid & (SPB - 1);
    int c   = (gid >> 5) & (C - 1);
    int b   = gid >> 12;
    int tid = threadIdx.x;
    int bs  = b * SPB + s;

    // prefetch everything coalesced, unconditionally (garbage slots unused)
    int   my_cnt = (tid == 0) ? cursor[bs] : 0;
    int   r0 = bucket[bs * CAP + tid];
    int   r1 = bucket[bs * CAP + 256 + tid];
    int   r2 = bucket[bs * CAP + 512 + tid];
    float4 xv = ((const float4*)(xT + (size_t)(b * C + c) * N))[tid];  // 1024 floats

    // zero acc while loads fly
    float4 z4 = make_float4(0.f, 0.f, 0.f, 0.f);
    ((float4*)acc)[tid]       = z4;
    ((float4*)acc)[tid + 256] = z4;

    if (tid == 0) cnt_s = my_cnt > CAP ? CAP : my_cnt;
    recs[tid]       = r0;
    recs[tid + 256] = r1;
    recs[tid + 512] = r2;
    ((float4*)xc)[tid] = xv;
    __syncthreads();

    int cnt = cnt_s;
    for (int j = tid; j < cnt; j += 256) {
        int e = recs[j];
        atomicAdd(&acc[e >> 10], xc[e & 1023]);
    }
    __syncthreads();

    // epilogue: divide by per-cell count and stream 8 KB contiguous
    const float4* nbase = (const float4*)(cnts + (size_t)b * HW + s * STRIP);
    float*        obase = out + ((size_t)(b * C + c) * HW + s * STRIP);
    #pragma unroll
    for (int i = 0; i < 2; ++i) {
        int i4 = i * 256 + tid;                 // 512 float4s
        float4 a = ((float4*)acc)[i4];
        float4 n = nbase[i4];                   // L2-hot (2 MB total)
        a.x /= (n.x + 1e-6f);
        a.y /= (n.y + 1e-6f);
        a.z /= (n.z + 1e-6f);
        a.w /= (n.w + 1e-6f);
        ((float4*)obase)[i4] = a;
    }
}

extern "C" void kernel_launch(void* const* d_in, const int* in_sizes, int n_in,
                              void* d_out, int out_size, void* d_ws, size_t ws_size,
                              hipStream_t stream) {
    const float* x        = (const float*)d_in[0];
    const float* loc_orig = (const float*)d_in[2];
    const int*   idx_agg  = (const int*)d_in[3];
    float* out = (float*)d_out;

    // ws layout: cursor[256] | cnts[B*HW] (2 MB) | bucket[NSTRIP*CAP] | xT (4 MB)
    int*   cursor = (int*)d_ws;
    float* cnts   = (float*)(cursor + 256);
    int*   bucket = (int*)(cnts + (size_t)B * HW);
    float* xT     = (float*)(bucket + NSTRIP * CAP);

    // one memset covers cursor + cnts (adjacent)
    hipMemsetAsync(cursor, 0, 256 * sizeof(int) + (size_t)B * HW * sizeof(float), stream);
    transpose_kernel<<<B * (N / 64), 256, 0, stream>>>(x, xT);
    bucket_kernel<<<(NPTS + 255) / 256, 256, 0, stream>>>(loc_orig, idx_agg, cursor, bucket, cnts);
    strip_kernel<<<B * C * SPB, 256, 0, stream>>>(xT, cursor, bucket, cnts, out);
}

// Round 9
// 356.637 us; speedup vs baseline: 1.1513x; 1.1513x over previous
//
#include <hip/hip_runtime.h>

// Problem constants (fixed by setup_inputs + SCALE_FACTOR=2 branch):
//   B=8, N=1024, C=128, N0=16384, output grid H=W=256
constexpr int B  = 8;
constexpr int N  = 1024;
constexpr int C  = 128;
constexpr int N0 = 16384;
constexpr int HH = 256;
constexpr int WW = 256;
constexpr int HW = HH * WW;                 // 65536 cells/batch
constexpr int NPTS = B * N0;                // 131072 points

constexpr int CPG  = 32;                    // cells per group
constexpr int GPB  = HW / CPG;              // 2048 groups/batch
constexpr int NGRP = B * GPB;               // 16384 groups
constexpr int CAP  = 96;                    // mean 8 points/group; 96 >> tail

constexpr int GPBLK = 8;                    // groups per persistent block
constexpr int NBLK  = NGRP / GPBLK;         // 2048 blocks = 8/CU x 256 CU, ONE round

constexpr int ROW  = CPG + 4;               // 36 words: rows 16B-aligned
constexpr int ACC_WORDS = C * ROW;          // 4608 words = 18 KB

// Bit-exact replica of the reference cell computation (validated R1-R8):
__device__ __forceinline__ int cell_of(float lx, float ly) {
    lx = fminf(fmaxf(lx, -1.0f), 1.0f);
    ly = fminf(fmaxf(ly, -1.0f), 1.0f);
    float pxf = rintf(0.5f * (lx + 1.0f) * 256.0f - 0.5f);  // RNE == jnp.round
    float pyf = rintf(0.5f * (ly + 1.0f) * 256.0f - 0.5f);
    int ix = (int)pxf; ix = ix < 0 ? 0 : (ix > WW - 1 ? WW - 1 : ix);
    int iy = (int)pyf; iy = iy < 0 ? 0 : (iy > HH - 1 ? HH - 1 : iy);
    return iy * WW + ix;
}

// ---- Pass 1: bucket points by 32-cell group (rec = local<<10 | tok) ------
__global__ void bucket_kernel(const float* __restrict__ loc_orig,
                              const int* __restrict__ idx_agg,
                              int* __restrict__ cursor,
                              int* __restrict__ bucket) {
    int p = blockIdx.x * blockDim.x + threadIdx.x;
    if (p >= NPTS) return;
    float2 l = ((const float2*)loc_orig)[p];
    int b = p >> 14;                            // N0 = 2^14
    int cell = cell_of(l.x, l.y);
    int g = b * GPB + (cell >> 5);              // CPG = 32
    int pos = atomicAdd(cursor + g, 1);
    if (pos < CAP) bucket[g * CAP + pos] = ((cell & 31) << 10) | idx_agg[p];
}

// ---- Pass 2: persistent pipelined gather. 2048 blocks, 8 groups each. ----
// One occupancy round; per-group phases pipelined (next recs prefetched into
// registers during current accumulate; acc re-zeroed inside the store pass).
__global__ __launch_bounds__(256, 8) void gather_kernel(
        const float* __restrict__ x,
        const int* __restrict__ cursor,
        const int* __restrict__ bucket,
        float* __restrict__ out) {
    __shared__ float acc[ACC_WORDS];            // [C][ROW] channel-major, 18 KB
    __shared__ float cntf[CPG];                 // per-cell counts (zeroed each group)
    __shared__ float scale[CPG];
    __shared__ int   recs[CAP];
    __shared__ int   cnt_s;

    int g0  = blockIdx.x * GPBLK;               // 8 consecutive groups, same batch
    int b   = g0 >> 11;                         // GPB = 2048
    int tid = threadIdx.x;
    int wave = tid >> 6, lane = tid & 63;

    // stage group 0 (loads fly over the LDS zero-fill)
    int r0 = (tid < CAP) ? bucket[g0 * CAP + tid] : 0;
    int c0 = (tid == 0) ? cursor[g0] : 0;

    float4 z4 = make_float4(0.f, 0.f, 0.f, 0.f);
    for (int i = tid; i < ACC_WORDS / 4; i += 256) ((float4*)acc)[i] = z4;
    if (tid < CPG) cntf[tid] = 0.0f;
    if (tid < CAP) recs[tid] = r0;
    if (tid == 0) cnt_s = c0 > CAP ? CAP : c0;
    __syncthreads();

    for (int k = 0; k < GPBLK; ++k) {
        int g     = g0 + k;
        int cell0 = (g & 2047) * CPG;

        // prefetch next group's records into registers (latency hides under
        // the accumulate phase; last iteration re-reads harmlessly)
        int gn = (k + 1 < GPBLK) ? g + 1 : g;
        int r_next = (tid < CAP) ? bucket[gn * CAP + tid] : 0;
        int c_next = (tid == 0) ? cursor[gn] : 0;

        // accumulate: one wave per point, lane covers channels 2l, 2l+1
        int cnt = cnt_s;
        for (int j = wave; j < cnt; j += 4) {
            int e = recs[j];
            int local = e >> 10;
            int tok   = e & 1023;
            float2 v = ((const float2*)(x + (size_t)(b * N + tok) * C))[lane];
            atomicAdd(&acc[(2 * lane)     * ROW + local], v.x);
            atomicAdd(&acc[(2 * lane + 1) * ROW + local], v.y);
            if (lane == 0) atomicAdd(&cntf[local], 1.0f);
        }
        __syncthreads();                        // atomics done; recs now free

        if (tid < CPG) { scale[tid] = 1.0f / (cntf[tid] + 1e-6f); cntf[tid] = 0.0f; }
        if (tid < CAP) recs[tid] = r_next;      // swap in next group's records
        if (tid == 0)  cnt_s = c_next > CAP ? CAP : c_next;
        __syncthreads();                        // scale ready; recs swapped

        // store pass: read acc -> scale -> store -> re-zero (same word, same
        // thread: each (c, cell-quad) word is read by exactly one thread)
        int i4 = (tid & 7) * 4;                 // cell quad
        int cb = tid >> 3;                      // 32 channels per unroll step
        float s0 = scale[i4 + 0], s1 = scale[i4 + 1];
        float s2 = scale[i4 + 2], s3 = scale[i4 + 3];
        float* obase = out + (size_t)b * C * HW + cell0;
        #pragma unroll
        for (int it = 0; it < 4; ++it) {
            int c = it * 32 + cb;
            float4 v = *(const float4*)&acc[c * ROW + i4];
            v.x *= s0; v.y *= s1; v.z *= s2; v.w *= s3;
            *(float4*)(obase + (size_t)c * HW + i4) = v;
            *(float4*)&acc[c * ROW + i4] = z4;  // re-zero for next group
        }
        __syncthreads();                        // acc clean before next atomics
    }
}

extern "C" void kernel_launch(void* const* d_in, const int* in_sizes, int n_in,
                              void* d_out, int out_size, void* d_ws, size_t ws_size,
                              hipStream_t stream) {
    const float* x        = (const float*)d_in[0];
    const float* loc_orig = (const float*)d_in[2];
    const int*   idx_agg  = (const int*)d_in[3];
    float* out = (float*)d_out;

    // workspace (ints): cursor[NGRP] (64 KB) | bucket[NGRP*CAP] (6.3 MB)
    int* cursor = (int*)d_ws;
    int* bucket = cursor + NGRP;

    hipMemsetAsync(cursor, 0, NGRP * sizeof(int), stream);
    bucket_kernel<<<(NPTS + 255) / 256, 256, 0, stream>>>(loc_orig, idx_agg, cursor, bucket);
    gather_kernel<<<NBLK, 256, 0, stream>>>(x, cursor, bucket, out);
}